// Round 4
// baseline (1105.314 us; speedup 1.0000x reference)
//
#include <hip/hip_runtime.h>
#include <stdint.h>

#define NN 8192
#define DH 512
#define NH 4
#define LOG2E 1.4426950408889634f

typedef __attribute__((ext_vector_type(8))) short short8;
typedef __attribute__((ext_vector_type(4))) float f32x4;

__device__ __forceinline__ unsigned short f2bf(float f) {
    unsigned int u = __float_as_uint(f);
    unsigned int r = (u + 0x7fffu + ((u >> 16) & 1u)) >> 16;
    return (unsigned short)r;
}

__device__ __forceinline__ void global_to_lds16(const void* g, void* l) {
    __builtin_amdgcn_global_load_lds(
        (const __attribute__((address_space(1))) unsigned int*)g,
        (__attribute__((address_space(3))) unsigned int*)l, 16, 0, 0);
}

// ---------------- kernel 0a: h fp32 -> bf16 ----------------
__global__ void k_convert_h(const float* __restrict__ hf, unsigned short* __restrict__ hb) {
    const int idx = (blockIdx.x * 256 + threadIdx.x) * 8;
    const float4 f0 = *(const float4*)(hf + idx);
    const float4 f1 = *(const float4*)(hf + idx + 4);
    uint4 o;
    o.x = (unsigned)f2bf(f0.x) | ((unsigned)f2bf(f0.y) << 16);
    o.y = (unsigned)f2bf(f0.z) | ((unsigned)f2bf(f0.w) << 16);
    o.z = (unsigned)f2bf(f1.x) | ((unsigned)f2bf(f1.y) << 16);
    o.w = (unsigned)f2bf(f1.z) | ((unsigned)f2bf(f1.w) << 16);
    *(uint4*)(hb + idx) = o;
}

// ---------------- kernel 0b: W (512x2048) fp32 -> Wt (2048x512) bf16 ----------------
__global__ void k_transpose_W(const float* __restrict__ W, unsigned short* __restrict__ Wt) {
    __shared__ float t[32][33];
    const int tx = threadIdx.x & 31, ty = threadIdx.x >> 5;
    const int p0 = blockIdx.x * 32, k0 = blockIdx.y * 32;
#pragma unroll
    for (int r = 0; r < 4; r++)
        t[ty + r * 8][tx] = W[(k0 + ty + r * 8) * 2048 + p0 + tx];
    __syncthreads();
#pragma unroll
    for (int r = 0; r < 4; r++)
        Wt[(size_t)(p0 + ty + r * 8) * 512 + k0 + tx] = f2bf(t[tx][ty + r * 8]);
}

// ---------------- kernel 1: vt = Wt @ hb^T, fused src/dst projections ----------------
__global__ __launch_bounds__(256, 3) void k_gemm(const unsigned short* __restrict__ Wt,
                                                 const unsigned short* __restrict__ hb,
                                                 unsigned short* __restrict__ vt,
                                                 const float* __restrict__ a,
                                                 float* __restrict__ srcL,
                                                 float* __restrict__ dstL) {
    __shared__ alignas(16) char smem[32768];
    const int tid = threadIdx.x;
    const int w = tid >> 6, lane = tid & 63;
    const int lr = lane & 15, lc = lane >> 4;
    const int pBase = blockIdx.y * 128, nBase = blockIdx.x * 128;
    f32x4 acc[4][4] = {};
    const int wr = (w >> 1) * 64, wc = (w & 1) * 64;
    for (int kb = 0; kb < 8; kb++) {
        const int k0 = kb * 64;
#pragma unroll
        for (int it = 0; it < 4; it++) {
            const int o = it * 4096 + w * 1024 + lane * 16;
            const int row = o >> 7;
            const int koff = (o & 127) >> 1;
            global_to_lds16(Wt + (size_t)(pBase + row) * 512 + k0 + koff,
                            smem + it * 4096 + w * 1024);
            global_to_lds16(hb + (size_t)(nBase + row) * 512 + k0 + koff,
                            smem + 16384 + it * 4096 + w * 1024);
        }
        __syncthreads();
#pragma unroll
        for (int kk = 0; kk < 2; kk++) {
            short8 av[4], bv[4];
#pragma unroll
            for (int m = 0; m < 4; m++)
                av[m] = *(const short8*)(smem + (wr + m * 16 + lr) * 128 + kk * 64 + lc * 16);
#pragma unroll
            for (int n = 0; n < 4; n++)
                bv[n] = *(const short8*)(smem + 16384 + (wc + n * 16 + lr) * 128 + kk * 64 + lc * 16);
#pragma unroll
            for (int m = 0; m < 4; m++)
#pragma unroll
                for (int n = 0; n < 4; n++)
                    acc[m][n] = __builtin_amdgcn_mfma_f32_16x16x32_bf16(av[m], bv[n], acc[m][n], 0, 0, 0);
        }
        __syncthreads();
    }
    // C write
#pragma unroll
    for (int m = 0; m < 4; m++)
#pragma unroll
        for (int n = 0; n < 4; n++)
#pragma unroll
            for (int q = 0; q < 4; q++) {
                const int p = pBase + wr + m * 16 + lc * 4 + q;
                const int ncol = nBase + wc + n * 16 + lr;
                vt[(size_t)p * NN + ncol] = f2bf(acc[m][n][q]);
            }
    // fused src/dst: this block's p-range lies in one head
    const int hh = pBase >> 9;
    const float* __restrict__ ah = a + hh * 1024;
    float ssum[4] = {0.f, 0.f, 0.f, 0.f}, tsum[4] = {0.f, 0.f, 0.f, 0.f};
#pragma unroll
    for (int m = 0; m < 4; m++) {
        const int dbase = (pBase & 511) + wr + m * 16 + lc * 4;
#pragma unroll
        for (int q = 0; q < 4; q++) {
            const float as = ah[dbase + q];
            const float ad = ah[512 + dbase + q];
#pragma unroll
            for (int n = 0; n < 4; n++) {
                ssum[n] += acc[m][n][q] * as;
                tsum[n] += acc[m][n][q] * ad;
            }
        }
    }
#pragma unroll
    for (int n = 0; n < 4; n++) {
        ssum[n] += __shfl_xor(ssum[n], 16, 64);
        ssum[n] += __shfl_xor(ssum[n], 32, 64);
        tsum[n] += __shfl_xor(tsum[n], 16, 64);
        tsum[n] += __shfl_xor(tsum[n], 32, 64);
    }
    if (lane < 16) {
#pragma unroll
        for (int n = 0; n < 4; n++) {
            const int ncol = nBase + wc + n * 16 + lane;
            __hip_atomic_fetch_add(&srcL[hh * NN + ncol], ssum[n] * LOG2E,
                                   __ATOMIC_RELAXED, __HIP_MEMORY_SCOPE_AGENT);
            __hip_atomic_fetch_add(&dstL[hh * NN + ncol], tsum[n] * LOG2E,
                                   __ATOMIC_RELAXED, __HIP_MEMORY_SCOPE_AGENT);
        }
    }
}

// ---------------- kernel 3: fused masked-softmax attention + PV + mean ----------------
// 256 blocks = (i-block 128 rows) x head; 8 waves; quad-buffered V, depth-2 adj reg
// prefetch, counted vmcnt(16), 1 raw barrier/tile.
#define NJT (NN / 32)
__global__ __launch_bounds__(512, 2) void k_flash(const float* __restrict__ adj,
                                                  const unsigned short* __restrict__ vt,
                                                  const float* __restrict__ srcL,
                                                  const float* __restrict__ dstL,
                                                  float* __restrict__ out) {
    __shared__ alignas(16) char smem[147968];  // V 4x32KB | P 2x8KB | denom 512B
    char* const vb0 = smem;
    char* const vb1 = smem + 32768;
    char* const vb2 = smem + 65536;
    char* const vb3 = smem + 98304;
    char* const p0lds = smem + 131072;
    char* const p1lds = smem + 139264;
    float* denom = (float*)(smem + 147456);

    const int tid = threadIdx.x;
    const int w = tid >> 6, lane = tid & 63;
    const int lr = lane & 15, lc = lane >> 4;
    const int h = blockIdx.x & 3;
    const int i0 = (int)(blockIdx.x >> 2) * 128;
    const int ih = w >> 2, dq = w & 3;

    const int srow = i0 + w * 16 + lr;
    const float srcv = srcL[h * NN + srow];
    const float* __restrict__ adjp = adj + (size_t)srow * NN + lc * 8;
    const float* __restrict__ dlp = dstL + h * NN + lc * 8;
    const unsigned short* __restrict__ vth = vt + (size_t)(h * 512) * NN;
    float dsum = 0.f;
    f32x4 acc[4][8] = {};

    // per-lane V-stage source offsets (element units), paired-row XOR layout
    unsigned voff[4];
#pragma unroll
    for (int it = 0; it < 4; it++) {
        const int o = it * 8192 + w * 1024 + lane * 16;
        const int row = o >> 7;
        const int z = ((o >> 4) & 7) ^ (row & 7);
        const int d = (row << 1) | (z >> 2);
        voff[it] = (unsigned)d * NN + ((z & 3) << 3);
    }
    // P write slot (row r = w*16+lr, j-chunk lc), paired-row XOR layout
    const int prow = w * 16 + lr;
    const int psl = (((prow & 1) << 2) | lc) ^ ((prow >> 1) & 7);
    const int poff = (prow >> 1) * 128 + (psl << 4);

#define STAGE(J0, DST)                                                                   \
    {                                                                                    \
        _Pragma("unroll") for (int it = 0; it < 4; it++)                                 \
            global_to_lds16(vth + voff[it] + (J0), (DST) + it * 8192 + w * 1024);        \
    }

#define LOADROW_A(J0)                                                                    \
    ajA0 = *(const float4*)(adjp + (J0));                                                \
    ajA1 = *(const float4*)(adjp + (J0) + 4);                                            \
    dlA0 = *(const float4*)(dlp + (J0));                                                 \
    dlA1 = *(const float4*)(dlp + (J0) + 4);

#define LOADROW_B(J0)                                                                    \
    ajB0 = *(const float4*)(adjp + (J0));                                                \
    ajB1 = *(const float4*)(adjp + (J0) + 4);                                            \
    dlB0 = *(const float4*)(dlp + (J0));                                                 \
    dlB1 = *(const float4*)(dlp + (J0) + 4);

#define SCORE_IMPL(AJ0, AJ1, DL0, DL1)                                                   \
    {                                                                                    \
        const float padj[8] = {AJ0.x, AJ0.y, AJ0.z, AJ0.w, AJ1.x, AJ1.y, AJ1.z, AJ1.w}; \
        const float pdst[8] = {DL0.x, DL0.y, DL0.z, DL0.w, DL1.x, DL1.y, DL1.z, DL1.w}; \
        float pv[8];                                                                     \
        _Pragma("unroll") for (int q = 0; q < 8; q++) {                                  \
            const float x = srcv + pdst[q];                                              \
            const float l2 = fmaxf(x, 0.01f * x);                                        \
            float e;                                                                     \
            asm("v_exp_f32 %0, %1" : "=v"(e) : "v"(l2 + padj[q]));                       \
            dsum += e;                                                                   \
            pv[q] = e;                                                                   \
        }                                                                                \
        union { unsigned u[4]; short8 s; } pk;                                           \
        asm("v_cvt_pk_bf16_f32 %0, %1, %2" : "=v"(pk.u[0]) : "v"(pv[0]), "v"(pv[1]));    \
        asm("v_cvt_pk_bf16_f32 %0, %1, %2" : "=v"(pk.u[1]) : "v"(pv[2]), "v"(pv[3]));    \
        asm("v_cvt_pk_bf16_f32 %0, %1, %2" : "=v"(pk.u[2]) : "v"(pv[4]), "v"(pv[5]));    \
        asm("v_cvt_pk_bf16_f32 %0, %1, %2" : "=v"(pk.u[3]) : "v"(pv[6]), "v"(pv[7]));    \
        pfrag = pk.s;                                                                    \
    }

#define SCORE_A() SCORE_IMPL(ajA0, ajA1, dlA0, dlA1)
#define SCORE_B() SCORE_IMPL(ajB0, ajB1, dlB0, dlB1)

#define PV(VBUF, PBUF)                                                                   \
    {                                                                                    \
        const char* vbp = (VBUF);                                                        \
        const char* pbp = (PBUF);                                                        \
        short8 afr[4];                                                                   \
        _Pragma("unroll") for (int t = 0; t < 4; t++) {                                  \
            const int rr = ih * 64 + t * 16 + lr;                                        \
            const int sl = (((rr & 1) << 2) | lc) ^ ((rr >> 1) & 7);                     \
            afr[t] = *(const short8*)(pbp + (rr >> 1) * 128 + (sl << 4));                \
        }                                                                                \
        __builtin_amdgcn_s_setprio(1);                                                   \
        _Pragma("unroll") for (int s = 0; s < 8; s++) {                                  \
            const int d = dq * 128 + s * 16 + lr;                                        \
            const int sl = (((d & 1) << 2) | lc) ^ ((d >> 1) & 7);                       \
            const short8 bfr = *(const short8*)(vbp + (d >> 1) * 128 + (sl << 4));       \
            _Pragma("unroll") for (int t = 0; t < 4; t++)                                \
                acc[t][s] = __builtin_amdgcn_mfma_f32_16x16x32_bf16(afr[t], bfr,         \
                                                                    acc[t][s], 0, 0, 0); \
        }                                                                                \
        __builtin_amdgcn_s_setprio(0);                                                   \
    }

#define WAITBAR(N)                                                                       \
    asm volatile("s_waitcnt vmcnt(" #N ") lgkmcnt(0)" ::: "memory");                     \
    __builtin_amdgcn_sched_barrier(0);                                                   \
    __builtin_amdgcn_s_barrier();                                                        \
    __builtin_amdgcn_sched_barrier(0);

// body for tile JB (JB % 4 == K): PV(tile JB), score tile JB+1, prefetch tile JB+2
#define BODY0(JB)                       \
    LOADROW_A(((JB) + 2) * 32);         \
    STAGE(((JB) + 2) * 32, vb2);        \
    WAITBAR(16);                        \
    PV(vb0, p0lds);                     \
    SCORE_B();                          \
    *(short8*)(p1lds + poff) = pfrag;
#define BODY1(JB)                       \
    LOADROW_B(((JB) + 2) * 32);         \
    STAGE(((JB) + 2) * 32, vb3);        \
    WAITBAR(16);                        \
    PV(vb1, p1lds);                     \
    SCORE_A();                          \
    *(short8*)(p0lds + poff) = pfrag;
#define BODY2(JB)                       \
    LOADROW_A(((JB) + 2) * 32);         \
    STAGE(((JB) + 2) * 32, vb0);        \
    WAITBAR(16);                        \
    PV(vb2, p0lds);                     \
    SCORE_B();                          \
    *(short8*)(p1lds + poff) = pfrag;
#define BODY3(JB)                       \
    LOADROW_B(((JB) + 2) * 32);         \
    STAGE(((JB) + 2) * 32, vb1);        \
    WAITBAR(16);                        \
    PV(vb3, p1lds);                     \
    SCORE_A();                          \
    *(short8*)(p0lds + poff) = pfrag;

    float4 ajA0, ajA1, dlA0, dlA1;
    float4 ajB0, ajB1, dlB0, dlB1;
    short8 pfrag;
    // ---- prologue: tiles 0,1 in flight; score tile 0 ----
    LOADROW_A(0);
    STAGE(0, vb0);
    LOADROW_B(32);
    STAGE(32, vb1);
    SCORE_A();
    *(short8*)(p0lds + poff) = pfrag;
    WAITBAR(8);  // V(0) resident; tile-1 loads stay in flight
    // ---- steady state ----
#pragma unroll 1
    for (int jb = 0; jb < NJT - 4; jb += 4) {
        BODY0(jb + 0);
        BODY1(jb + 1);
        BODY2(jb + 2);
        BODY3(jb + 3);
    }
    BODY0(NJT - 4);  // jb=252
    BODY1(NJT - 3);  // jb=253
    // ---- tail: tile 254 (K=2) ----
    WAITBAR(8);
    PV(vb2, p0lds);
    SCORE_B();
    *(short8*)(p1lds + poff) = pfrag;
    // ---- tail: tile 255 (K=3) ----
    WAITBAR(0);
    PV(vb3, p1lds);

    // --- denominators: reduce 4 lane-partials per row ---
    dsum += __shfl_xor(dsum, 16, 64);
    dsum += __shfl_xor(dsum, 32, 64);
    if (lane < 16) denom[w * 16 + lane] = dsum;
    __syncthreads();
    // --- epilogue: out[i][d] += 0.25 * acc / denom ---
#pragma unroll
    for (int t = 0; t < 4; t++) {
        const int rl = ih * 64 + t * 16 + lc * 4;
#pragma unroll
        for (int q = 0; q < 4; q++) {
            const float inv = 0.25f / denom[rl + q];
            float* orow = out + (size_t)(i0 + rl + q) * 512;
#pragma unroll
            for (int s = 0; s < 8; s++) {
                const int d = dq * 128 + s * 16 + lr;
                __hip_atomic_fetch_add(orow + d, acc[t][s][q] * inv,
                                       __ATOMIC_RELAXED, __HIP_MEMORY_SCOPE_AGENT);
            }
        }
    }
}

extern "C" void kernel_launch(void* const* d_in, const int* in_sizes, int n_in,
                              void* d_out, int out_size, void* d_ws, size_t ws_size,
                              hipStream_t stream) {
    const float* h = (const float*)d_in[0];
    const float* adj = (const float*)d_in[1];
    const float* W = (const float*)d_in[2];
    const float* a = (const float*)d_in[3];
    float* out = (float*)d_out;
    char* ws = (char*)d_ws;
    unsigned short* hb = (unsigned short*)ws;                                  // 8 MB
    unsigned short* Wt = (unsigned short*)(ws + 8388608);                      // 2 MB
    unsigned short* vt = (unsigned short*)(ws + 8388608 + 2097152);            // 32 MB
    float* srcL = (float*)(ws + 8388608 + 2097152 + 33554432);                 // 128 KB
    float* dstL = srcL + NH * NN;                                              // 128 KB

    hipMemsetAsync(d_out, 0, (size_t)out_size * sizeof(float), stream);
    hipMemsetAsync(srcL, 0, 2 * NH * NN * sizeof(float), stream);
    k_convert_h<<<2048, 256, 0, stream>>>(h, hb);
    k_transpose_W<<<dim3(64, 16), 256, 0, stream>>>(W, Wt);
    k_gemm<<<dim3(64, 16), 256, 0, stream>>>(Wt, hb, vt, a, srcL, dstL);
    k_flash<<<256, 512, 0, stream>>>(adj, vt, srcL, dstL, out);
}

// Round 6
// 1057.577 us; speedup vs baseline: 1.0451x; 1.0451x over previous
//
#include <hip/hip_runtime.h>
#include <stdint.h>

#define NN 8192
#define DH 512
#define NH 4
#define LOG2E 1.4426950408889634f

typedef __attribute__((ext_vector_type(8))) short short8;
typedef __attribute__((ext_vector_type(4))) float f32x4;

__device__ __forceinline__ unsigned short f2bf(float f) {
    unsigned int u = __float_as_uint(f);
    unsigned int r = (u + 0x7fffu + ((u >> 16) & 1u)) >> 16;
    return (unsigned short)r;
}

__device__ __forceinline__ void global_to_lds16(const void* g, void* l) {
    __builtin_amdgcn_global_load_lds(
        (const __attribute__((address_space(1))) unsigned int*)g,
        (__attribute__((address_space(3))) unsigned int*)l, 16, 0, 0);
}

// ---------------- kernel 0a: h fp32 -> bf16 ----------------
__global__ void k_convert_h(const float* __restrict__ hf, unsigned short* __restrict__ hb) {
    const int idx = (blockIdx.x * 256 + threadIdx.x) * 8;
    const float4 f0 = *(const float4*)(hf + idx);
    const float4 f1 = *(const float4*)(hf + idx + 4);
    uint4 o;
    o.x = (unsigned)f2bf(f0.x) | ((unsigned)f2bf(f0.y) << 16);
    o.y = (unsigned)f2bf(f0.z) | ((unsigned)f2bf(f0.w) << 16);
    o.z = (unsigned)f2bf(f1.x) | ((unsigned)f2bf(f1.y) << 16);
    o.w = (unsigned)f2bf(f1.z) | ((unsigned)f2bf(f1.w) << 16);
    *(uint4*)(hb + idx) = o;
}

// ---------------- kernel 0b: W (512x2048) fp32 -> Wt (2048x512) bf16 ----------------
__global__ void k_transpose_W(const float* __restrict__ W, unsigned short* __restrict__ Wt) {
    __shared__ float t[32][33];
    const int tx = threadIdx.x & 31, ty = threadIdx.x >> 5;
    const int p0 = blockIdx.x * 32, k0 = blockIdx.y * 32;
#pragma unroll
    for (int r = 0; r < 4; r++)
        t[ty + r * 8][tx] = W[(k0 + ty + r * 8) * 2048 + p0 + tx];
    __syncthreads();
#pragma unroll
    for (int r = 0; r < 4; r++)
        Wt[(size_t)(p0 + ty + r * 8) * 512 + k0 + tx] = f2bf(t[tx][ty + r * 8]);
}

// ---------------- kernel 1: vt = Wt @ hb^T, fused src/dst projections ----------------
__global__ __launch_bounds__(256, 3) void k_gemm(const unsigned short* __restrict__ Wt,
                                                 const unsigned short* __restrict__ hb,
                                                 unsigned short* __restrict__ vt,
                                                 const float* __restrict__ a,
                                                 float* __restrict__ srcL,
                                                 float* __restrict__ dstL) {
    __shared__ alignas(16) char smem[32768];
    const int tid = threadIdx.x;
    const int w = tid >> 6, lane = tid & 63;
    const int lr = lane & 15, lc = lane >> 4;
    const int pBase = blockIdx.y * 128, nBase = blockIdx.x * 128;
    f32x4 acc[4][4] = {};
    const int wr = (w >> 1) * 64, wc = (w & 1) * 64;
    for (int kb = 0; kb < 8; kb++) {
        const int k0 = kb * 64;
#pragma unroll
        for (int it = 0; it < 4; it++) {
            const int o = it * 4096 + w * 1024 + lane * 16;
            const int row = o >> 7;
            const int koff = (o & 127) >> 1;
            global_to_lds16(Wt + (size_t)(pBase + row) * 512 + k0 + koff,
                            smem + it * 4096 + w * 1024);
            global_to_lds16(hb + (size_t)(nBase + row) * 512 + k0 + koff,
                            smem + 16384 + it * 4096 + w * 1024);
        }
        __syncthreads();
#pragma unroll
        for (int kk = 0; kk < 2; kk++) {
            short8 av[4], bv[4];
#pragma unroll
            for (int m = 0; m < 4; m++)
                av[m] = *(const short8*)(smem + (wr + m * 16 + lr) * 128 + kk * 64 + lc * 16);
#pragma unroll
            for (int n = 0; n < 4; n++)
                bv[n] = *(const short8*)(smem + 16384 + (wc + n * 16 + lr) * 128 + kk * 64 + lc * 16);
#pragma unroll
            for (int m = 0; m < 4; m++)
#pragma unroll
                for (int n = 0; n < 4; n++)
                    acc[m][n] = __builtin_amdgcn_mfma_f32_16x16x32_bf16(av[m], bv[n], acc[m][n], 0, 0, 0);
        }
        __syncthreads();
    }
#pragma unroll
    for (int m = 0; m < 4; m++)
#pragma unroll
        for (int n = 0; n < 4; n++)
#pragma unroll
            for (int q = 0; q < 4; q++) {
                const int p = pBase + wr + m * 16 + lc * 4 + q;
                const int ncol = nBase + wc + n * 16 + lr;
                vt[(size_t)p * NN + ncol] = f2bf(acc[m][n][q]);
            }
    const int hh = pBase >> 9;
    const float* __restrict__ ah = a + hh * 1024;
    float ssum[4] = {0.f, 0.f, 0.f, 0.f}, tsum[4] = {0.f, 0.f, 0.f, 0.f};
#pragma unroll
    for (int m = 0; m < 4; m++) {
        const int dbase = (pBase & 511) + wr + m * 16 + lc * 4;
#pragma unroll
        for (int q = 0; q < 4; q++) {
            const float as = ah[dbase + q];
            const float ad = ah[512 + dbase + q];
#pragma unroll
            for (int n = 0; n < 4; n++) {
                ssum[n] += acc[m][n][q] * as;
                tsum[n] += acc[m][n][q] * ad;
            }
        }
    }
#pragma unroll
    for (int n = 0; n < 4; n++) {
        ssum[n] += __shfl_xor(ssum[n], 16, 64);
        ssum[n] += __shfl_xor(ssum[n], 32, 64);
        tsum[n] += __shfl_xor(tsum[n], 16, 64);
        tsum[n] += __shfl_xor(tsum[n], 32, 64);
    }
    if (lane < 16) {
#pragma unroll
        for (int n = 0; n < 4; n++) {
            const int ncol = nBase + wc + n * 16 + lane;
            __hip_atomic_fetch_add(&srcL[hh * NN + ncol], ssum[n] * LOG2E,
                                   __ATOMIC_RELAXED, __HIP_MEMORY_SCOPE_AGENT);
            __hip_atomic_fetch_add(&dstL[hh * NN + ncol], tsum[n] * LOG2E,
                                   __ATOMIC_RELAXED, __HIP_MEMORY_SCOPE_AGENT);
        }
    }
}

// ---------------- kernel 3: fused masked-softmax attention + PV + mean ----------------
// 256 blocks = (i-block 128 rows) x head; 8 waves. V triple-buffered depth-1 (R2-proven
// sync), dstL in LDS (once), adj 3 reg sets loaded 3 tiles ahead, vmcnt(6)/body.
#define NJT (NN / 32)
__global__ __launch_bounds__(512, 2) void k_flash(const float* __restrict__ adj,
                                                  const unsigned short* __restrict__ vt,
                                                  const float* __restrict__ srcL,
                                                  const float* __restrict__ dstL,
                                                  float* __restrict__ out) {
    __shared__ alignas(16) char smem[147968];  // V 3x32K | dstL 32K | P 2x8K | denom 512B
    char* const vb0 = smem;
    char* const vb1 = smem + 32768;
    char* const vb2 = smem + 65536;
    char* const dstl = smem + 98304;
    char* const p0lds = smem + 131072;
    char* const p1lds = smem + 139264;
    float* denom = (float*)(smem + 147456);

    const int tid = threadIdx.x;
    const int w = tid >> 6, lane = tid & 63;
    const int lr = lane & 15, lc = lane >> 4;
    const int h = blockIdx.x & 3;
    const int i0 = (int)(blockIdx.x >> 2) * 128;
    const int ih = w >> 2, dq = w & 3;

    const int srow = i0 + w * 16 + lr;
    const float srcv = srcL[h * NN + srow];
    const float* __restrict__ adjp = adj + (size_t)srow * NN + lc * 8;
    const float* __restrict__ dlg = dstL + h * NN;
    const unsigned short* __restrict__ vth = vt + (size_t)(h * 512) * NN;
    float dsum = 0.f;
    f32x4 acc[4][8] = {};

    // per-lane V-stage source offsets (element units), paired-row XOR layout
    unsigned voff[4];
#pragma unroll
    for (int it = 0; it < 4; it++) {
        const int o = it * 8192 + w * 1024 + lane * 16;
        const int row = o >> 7;
        const int z = ((o >> 4) & 7) ^ (row & 7);
        const int d = (row << 1) | (z >> 2);
        voff[it] = (unsigned)d * NN + ((z & 3) << 3);
    }
    // P write slot (row r = w*16+lr, j-chunk lc), paired-row XOR layout
    const int prow = w * 16 + lr;
    const int psl = (((prow & 1) << 2) | lc) ^ ((prow >> 1) & 7);
    const int poff = (prow >> 1) * 128 + (psl << 4);

#define STAGE(J0, DST)                                                                   \
    {                                                                                    \
        _Pragma("unroll") for (int it = 0; it < 4; it++)                                 \
            global_to_lds16(vth + voff[it] + (J0), (DST) + it * 8192 + w * 1024);        \
    }

#define LOADROW_A(J0)                                                                    \
    ajA0 = *(const float4*)(adjp + (J0));                                                \
    ajA1 = *(const float4*)(adjp + (J0) + 4);

#define LOADROW_B(J0)                                                                    \
    ajB0 = *(const float4*)(adjp + (J0));                                                \
    ajB1 = *(const float4*)(adjp + (J0) + 4);

#define LOADROW_C(J0)                                                                    \
    ajC0 = *(const float4*)(adjp + (J0));                                                \
    ajC1 = *(const float4*)(adjp + (J0) + 4);

#define SCORE_IMPL(AJ0, AJ1, J0)                                                         \
    {                                                                                    \
        const float4 dl0 = *(const float4*)(dstl + ((J0) + lc * 8) * 4);                 \
        const float4 dl1 = *(const float4*)(dstl + ((J0) + lc * 8) * 4 + 16);            \
        const float padj[8] = {AJ0.x, AJ0.y, AJ0.z, AJ0.w, AJ1.x, AJ1.y, AJ1.z, AJ1.w}; \
        const float pdst[8] = {dl0.x, dl0.y, dl0.z, dl0.w, dl1.x, dl1.y, dl1.z, dl1.w}; \
        float pv[8];                                                                     \
        _Pragma("unroll") for (int q = 0; q < 8; q++) {                                  \
            const float x = srcv + pdst[q];                                              \
            const float l2 = fmaxf(x, 0.01f * x);                                        \
            float e;                                                                     \
            asm("v_exp_f32 %0, %1" : "=v"(e) : "v"(l2 + padj[q]));                       \
            dsum += e;                                                                   \
            pv[q] = e;                                                                   \
        }                                                                                \
        union { unsigned u[4]; short8 s; } pk;                                           \
        asm("v_cvt_pk_bf16_f32 %0, %1, %2" : "=v"(pk.u[0]) : "v"(pv[0]), "v"(pv[1]));    \
        asm("v_cvt_pk_bf16_f32 %0, %1, %2" : "=v"(pk.u[1]) : "v"(pv[2]), "v"(pv[3]));    \
        asm("v_cvt_pk_bf16_f32 %0, %1, %2" : "=v"(pk.u[2]) : "v"(pv[4]), "v"(pv[5]));    \
        asm("v_cvt_pk_bf16_f32 %0, %1, %2" : "=v"(pk.u[3]) : "v"(pv[6]), "v"(pv[7]));    \
        pfrag = pk.s;                                                                    \
    }

#define SCORE_A(J0) SCORE_IMPL(ajA0, ajA1, J0)
#define SCORE_B(J0) SCORE_IMPL(ajB0, ajB1, J0)
#define SCORE_C(J0) SCORE_IMPL(ajC0, ajC1, J0)

#define PV(VBUF, PBUF)                                                                   \
    {                                                                                    \
        const char* vbp = (VBUF);                                                        \
        const char* pbp = (PBUF);                                                        \
        short8 afr[4];                                                                   \
        _Pragma("unroll") for (int t = 0; t < 4; t++) {                                  \
            const int rr = ih * 64 + t * 16 + lr;                                        \
            const int sl = (((rr & 1) << 2) | lc) ^ ((rr >> 1) & 7);                     \
            afr[t] = *(const short8*)(pbp + (rr >> 1) * 128 + (sl << 4));                \
        }                                                                                \
        __builtin_amdgcn_s_setprio(1);                                                   \
        _Pragma("unroll") for (int s = 0; s < 8; s++) {                                  \
            const int d = dq * 128 + s * 16 + lr;                                        \
            const int sl = (((d & 1) << 2) | lc) ^ ((d >> 1) & 7);                       \
            const short8 bfr = *(const short8*)(vbp + (d >> 1) * 128 + (sl << 4));       \
            _Pragma("unroll") for (int t = 0; t < 4; t++)                                \
                acc[t][s] = __builtin_amdgcn_mfma_f32_16x16x32_bf16(afr[t], bfr,         \
                                                                    acc[t][s], 0, 0, 0); \
        }                                                                                \
        __builtin_amdgcn_s_setprio(0);                                                   \
    }

#define WAITBAR(N)                                                                       \
    asm volatile("s_waitcnt vmcnt(" #N ") lgkmcnt(0)" ::: "memory");                     \
    __builtin_amdgcn_sched_barrier(0);                                                   \
    __builtin_amdgcn_s_barrier();                                                        \
    __builtin_amdgcn_sched_barrier(0);

// body(jb): prefetch adj tile jb+3 (regs) + V tile jb+1 (LDS, depth-1);
// then barrier, PV(tile jb), score tile jb+1, write P(jb+1). 6 vmem ops/body.
#define BODY(JB, VC_, VS_, PR_, PW_, LR_, SC_)  \
    LR_((JB) >= 253 ? 8160 : ((JB) + 3) * 32);  \
    STAGE(((JB) + 1) * 32, VS_);                \
    WAITBAR(6);                                 \
    PV(VC_, PR_);                               \
    SC_(((JB) + 1) * 32);                       \
    *(short8*)(PW_ + poff) = pfrag;

    float4 ajA0, ajA1, ajB0, ajB1, ajC0, ajC1;
    short8 pfrag;
    // ---- prologue: dstL->LDS, adj tiles 0,1,2 -> sets A,B,C, V tile 0 -> vb0 ----
#pragma unroll
    for (int p = 0; p < 4; p++)
        global_to_lds16(dlg + p * 2048 + w * 256 + lane * 4, dstl + p * 8192 + w * 1024);
    LOADROW_A(0);
    LOADROW_B(32);
    LOADROW_C(64);
    STAGE(0, vb0);
    WAITBAR(0);   // drain everything; dstl/adj/V(0) all resident
    SCORE_A(0);
    *(short8*)(p0lds + poff) = pfrag;
    // ---- steady state: 6-unrolled bodies (V mod 3, P mod 2, adj sets mod 3) ----
#pragma unroll 1
    for (int jb = 0; jb < 252; jb += 6) {
        BODY(jb + 0, vb0, vb1, p0lds, p1lds, LOADROW_A, SCORE_B);
        BODY(jb + 1, vb1, vb2, p1lds, p0lds, LOADROW_B, SCORE_C);
        BODY(jb + 2, vb2, vb0, p0lds, p1lds, LOADROW_C, SCORE_A);
        BODY(jb + 3, vb0, vb1, p1lds, p0lds, LOADROW_A, SCORE_B);
        BODY(jb + 4, vb1, vb2, p0lds, p1lds, LOADROW_B, SCORE_C);
        BODY(jb + 5, vb2, vb0, p1lds, p0lds, LOADROW_C, SCORE_A);
    }
    BODY(252, vb0, vb1, p0lds, p1lds, LOADROW_A, SCORE_B);
    BODY(253, vb1, vb2, p1lds, p0lds, LOADROW_B, SCORE_C);
    BODY(254, vb2, vb0, p0lds, p1lds, LOADROW_C, SCORE_A);
    // ---- tail: tile 255 (staged into vb0 at body 254, P in p1) ----
    WAITBAR(0);
    PV(vb0, p1lds);

    // --- denominators: reduce 4 lane-partials per row ---
    dsum += __shfl_xor(dsum, 16, 64);
    dsum += __shfl_xor(dsum, 32, 64);
    if (lane < 16) denom[w * 16 + lane] = dsum;
    __syncthreads();
    // --- epilogue: out[i][d] += 0.25 * acc / denom ---
#pragma unroll
    for (int t = 0; t < 4; t++) {
        const int rl = ih * 64 + t * 16 + lc * 4;
#pragma unroll
        for (int q = 0; q < 4; q++) {
            const float inv = 0.25f / denom[rl + q];
            float* orow = out + (size_t)(i0 + rl + q) * 512;
#pragma unroll
            for (int s = 0; s < 8; s++) {
                const int d = dq * 128 + s * 16 + lr;
                __hip_atomic_fetch_add(orow + d, acc[t][s][q] * inv,
                                       __ATOMIC_RELAXED, __HIP_MEMORY_SCOPE_AGENT);
            }
        }
    }
}

extern "C" void kernel_launch(void* const* d_in, const int* in_sizes, int n_in,
                              void* d_out, int out_size, void* d_ws, size_t ws_size,
                              hipStream_t stream) {
    const float* h = (const float*)d_in[0];
    const float* adj = (const float*)d_in[1];
    const float* W = (const float*)d_in[2];
    const float* a = (const float*)d_in[3];
    float* out = (float*)d_out;
    char* ws = (char*)d_ws;
    unsigned short* hb = (unsigned short*)ws;                                  // 8 MB
    unsigned short* Wt = (unsigned short*)(ws + 8388608);                      // 2 MB
    unsigned short* vt = (unsigned short*)(ws + 8388608 + 2097152);            // 32 MB
    float* srcL = (float*)(ws + 8388608 + 2097152 + 33554432);                 // 128 KB
    float* dstL = srcL + NH * NN;                                              // 128 KB

    hipMemsetAsync(d_out, 0, (size_t)out_size * sizeof(float), stream);
    hipMemsetAsync(srcL, 0, 2 * NH * NN * sizeof(float), stream);
    k_convert_h<<<2048, 256, 0, stream>>>(h, hb);
    k_transpose_W<<<dim3(64, 16), 256, 0, stream>>>(W, Wt);
    k_gemm<<<dim3(64, 16), 256, 0, stream>>>(Wt, hb, vt, a, srcL, dstL);
    k_flash<<<256, 512, 0, stream>>>(adj, vt, srcL, dstL, out);
}

// Round 7
// 862.719 us; speedup vs baseline: 1.2812x; 1.2259x over previous
//
#include <hip/hip_runtime.h>
#include <stdint.h>

#define NN 8192
#define DH 512
#define NH 4
#define LOG2E 1.4426950408889634f

typedef __attribute__((ext_vector_type(8))) short short8;
typedef __attribute__((ext_vector_type(4))) float f32x4;

__device__ __forceinline__ unsigned short f2bf(float f) {
    unsigned int u = __float_as_uint(f);
    unsigned int r = (u + 0x7fffu + ((u >> 16) & 1u)) >> 16;
    return (unsigned short)r;
}

__device__ __forceinline__ void global_to_lds16(const void* g, void* l) {
    __builtin_amdgcn_global_load_lds(
        (const __attribute__((address_space(1))) unsigned int*)g,
        (__attribute__((address_space(3))) unsigned int*)l, 16, 0, 0);
}

// ---------------- kernel 0a: h fp32 -> bf16 ----------------
__global__ void k_convert_h(const float* __restrict__ hf, unsigned short* __restrict__ hb) {
    const int idx = (blockIdx.x * 256 + threadIdx.x) * 8;
    const float4 f0 = *(const float4*)(hf + idx);
    const float4 f1 = *(const float4*)(hf + idx + 4);
    uint4 o;
    o.x = (unsigned)f2bf(f0.x) | ((unsigned)f2bf(f0.y) << 16);
    o.y = (unsigned)f2bf(f0.z) | ((unsigned)f2bf(f0.w) << 16);
    o.z = (unsigned)f2bf(f1.x) | ((unsigned)f2bf(f1.y) << 16);
    o.w = (unsigned)f2bf(f1.z) | ((unsigned)f2bf(f1.w) << 16);
    *(uint4*)(hb + idx) = o;
}

// ---------------- kernel 0b: W (512x2048) fp32 -> Wt (2048x512) bf16 ----------------
__global__ void k_transpose_W(const float* __restrict__ W, unsigned short* __restrict__ Wt) {
    __shared__ float t[32][33];
    const int tx = threadIdx.x & 31, ty = threadIdx.x >> 5;
    const int p0 = blockIdx.x * 32, k0 = blockIdx.y * 32;
#pragma unroll
    for (int r = 0; r < 4; r++)
        t[ty + r * 8][tx] = W[(k0 + ty + r * 8) * 2048 + p0 + tx];
    __syncthreads();
#pragma unroll
    for (int r = 0; r < 4; r++)
        Wt[(size_t)(p0 + ty + r * 8) * 512 + k0 + tx] = f2bf(t[tx][ty + r * 8]);
}

// ---------------- kernel 1: vt = Wt @ hb^T, fused src/dst projections ----------------
__global__ __launch_bounds__(256, 3) void k_gemm(const unsigned short* __restrict__ Wt,
                                                 const unsigned short* __restrict__ hb,
                                                 unsigned short* __restrict__ vt,
                                                 const float* __restrict__ a,
                                                 float* __restrict__ srcL,
                                                 float* __restrict__ dstL) {
    __shared__ alignas(16) char smem[32768];
    const int tid = threadIdx.x;
    const int w = tid >> 6, lane = tid & 63;
    const int lr = lane & 15, lc = lane >> 4;
    const int pBase = blockIdx.y * 128, nBase = blockIdx.x * 128;
    f32x4 acc[4][4] = {};
    const int wr = (w >> 1) * 64, wc = (w & 1) * 64;
    for (int kb = 0; kb < 8; kb++) {
        const int k0 = kb * 64;
#pragma unroll
        for (int it = 0; it < 4; it++) {
            const int o = it * 4096 + w * 1024 + lane * 16;
            const int row = o >> 7;
            const int koff = (o & 127) >> 1;
            global_to_lds16(Wt + (size_t)(pBase + row) * 512 + k0 + koff,
                            smem + it * 4096 + w * 1024);
            global_to_lds16(hb + (size_t)(nBase + row) * 512 + k0 + koff,
                            smem + 16384 + it * 4096 + w * 1024);
        }
        __syncthreads();
#pragma unroll
        for (int kk = 0; kk < 2; kk++) {
            short8 av[4], bv[4];
#pragma unroll
            for (int m = 0; m < 4; m++)
                av[m] = *(const short8*)(smem + (wr + m * 16 + lr) * 128 + kk * 64 + lc * 16);
#pragma unroll
            for (int n = 0; n < 4; n++)
                bv[n] = *(const short8*)(smem + 16384 + (wc + n * 16 + lr) * 128 + kk * 64 + lc * 16);
#pragma unroll
            for (int m = 0; m < 4; m++)
#pragma unroll
                for (int n = 0; n < 4; n++)
                    acc[m][n] = __builtin_amdgcn_mfma_f32_16x16x32_bf16(av[m], bv[n], acc[m][n], 0, 0, 0);
        }
        __syncthreads();
    }
#pragma unroll
    for (int m = 0; m < 4; m++)
#pragma unroll
        for (int n = 0; n < 4; n++)
#pragma unroll
            for (int q = 0; q < 4; q++) {
                const int p = pBase + wr + m * 16 + lc * 4 + q;
                const int ncol = nBase + wc + n * 16 + lr;
                vt[(size_t)p * NN + ncol] = f2bf(acc[m][n][q]);
            }
    const int hh = pBase >> 9;
    const float* __restrict__ ah = a + hh * 1024;
    float ssum[4] = {0.f, 0.f, 0.f, 0.f}, tsum[4] = {0.f, 0.f, 0.f, 0.f};
#pragma unroll
    for (int m = 0; m < 4; m++) {
        const int dbase = (pBase & 511) + wr + m * 16 + lc * 4;
#pragma unroll
        for (int q = 0; q < 4; q++) {
            const float as = ah[dbase + q];
            const float ad = ah[512 + dbase + q];
#pragma unroll
            for (int n = 0; n < 4; n++) {
                ssum[n] += acc[m][n][q] * as;
                tsum[n] += acc[m][n][q] * ad;
            }
        }
    }
#pragma unroll
    for (int n = 0; n < 4; n++) {
        ssum[n] += __shfl_xor(ssum[n], 16, 64);
        ssum[n] += __shfl_xor(ssum[n], 32, 64);
        tsum[n] += __shfl_xor(tsum[n], 16, 64);
        tsum[n] += __shfl_xor(tsum[n], 32, 64);
    }
    if (lane < 16) {
#pragma unroll
        for (int n = 0; n < 4; n++) {
            const int ncol = nBase + wc + n * 16 + lane;
            __hip_atomic_fetch_add(&srcL[hh * NN + ncol], ssum[n] * LOG2E,
                                   __ATOMIC_RELAXED, __HIP_MEMORY_SCOPE_AGENT);
            __hip_atomic_fetch_add(&dstL[hh * NN + ncol], tsum[n] * LOG2E,
                                   __ATOMIC_RELAXED, __HIP_MEMORY_SCOPE_AGENT);
        }
    }
}

// ---------------- kernel 3: fused masked-softmax attention + PV + mean ----------------
// 256 blocks; h=bid>>6, i0=(bid&63)*128 (XCD-friendly: 4 heads of one adj row-block share
// an XCD). 8 waves. V triple-buf (depth-1), adj triple-buf LDS staged 2 ahead (swizzled
// source, conflict-free reads), dstL L2-hot in-body regs, P double-buf. vmcnt(8)/body.
#define NJT (NN / 32)
__global__ __launch_bounds__(512, 2) void k_flash(const float* __restrict__ adj,
                                                  const unsigned short* __restrict__ vt,
                                                  const float* __restrict__ srcL,
                                                  const float* __restrict__ dstL,
                                                  float* __restrict__ out) {
    __shared__ alignas(16) char smem[163840];  // V 3x32K | adj 3x16K | P 2x8K
    char* const vb0 = smem;
    char* const vb1 = smem + 32768;
    char* const vb2 = smem + 65536;
    char* const ab0 = smem + 98304;
    char* const ab1 = smem + 114688;
    char* const ab2 = smem + 131072;
    char* const pb0 = smem + 147456;
    char* const pb1 = smem + 155648;
    float* denom = (float*)(smem + 98304);  // reuse ab0 after the loop

    const int tid = threadIdx.x;
    const int w = tid >> 6, lane = tid & 63;
    const int lr = lane & 15, lc = lane >> 4;
    const int h = (int)(blockIdx.x >> 6);
    const int i0 = (int)(blockIdx.x & 63) * 128;
    const int ih = w >> 2, dq = w & 3;

    const int srow = i0 + w * 16 + lr;
    const float srcv = srcL[h * NN + srow];
    const float* __restrict__ dlp = dstL + h * NN + lc * 8;
    const unsigned short* __restrict__ vth = vt + (size_t)(h * 512) * NN;
    float dsum = 0.f;
    f32x4 acc[4][8] = {};

    // V stage source offsets (element units), paired-row XOR layout
    unsigned voff[4];
#pragma unroll
    for (int it = 0; it < 4; it++) {
        const int o = it * 8192 + w * 1024 + lane * 16;
        const int row = o >> 7;
        const int z = ((o >> 4) & 7) ^ (row & 7);
        const int d = (row << 1) | (z >> 2);
        voff[it] = (unsigned)d * NN + ((z & 3) << 3);
    }
    // adj stage source offsets (floats, rel. to adj + J0): granule g holds half-chunk g^(row&7)
    unsigned aoff[2];
#pragma unroll
    for (int it = 0; it < 2; it++) {
        const int o = it * 8192 + w * 1024 + lane * 16;
        const int row = o >> 7;
        const int hc = ((o >> 4) & 7) ^ (row & 7);
        aoff[it] = (unsigned)(i0 + row) * NN + hc * 4;
    }
    // adj LDS read byte offsets (row = w*16+lr, half-chunks 2lc, 2lc+1)
    const int rladj = w * 16 + lr;
    const int g1 = (2 * lc) ^ (lr & 7);
    const int ar1 = rladj * 128 + (g1 << 4);
    const int ar2 = rladj * 128 + ((g1 ^ 1) << 4);
    // P write slot (row r = w*16+lr, j-chunk lc), paired-row XOR layout
    const int prow = w * 16 + lr;
    const int psl = (((prow & 1) << 2) | lc) ^ ((prow >> 1) & 7);
    const int poff = (prow >> 1) * 128 + (psl << 4);

#define STAGE(J0, DST)                                                                   \
    {                                                                                    \
        _Pragma("unroll") for (int it = 0; it < 4; it++)                                 \
            global_to_lds16(vth + voff[it] + (J0), (DST) + it * 8192 + w * 1024);        \
    }

#define STAGE_ADJ(J0, DST)                                                               \
    {                                                                                    \
        _Pragma("unroll") for (int it = 0; it < 2; it++)                                 \
            global_to_lds16(adj + aoff[it] + (J0), (DST) + it * 8192 + w * 1024);        \
    }

#define SCORE(AR_, J0)                                                                   \
    {                                                                                    \
        const float4 aj0 = *(const float4*)((AR_) + ar1);                                \
        const float4 aj1 = *(const float4*)((AR_) + ar2);                                \
        const float padj[8] = {aj0.x, aj0.y, aj0.z, aj0.w, aj1.x, aj1.y, aj1.z, aj1.w};  \
        const float pdst[8] = {dlA0.x, dlA0.y, dlA0.z, dlA0.w,                           \
                               dlA1.x, dlA1.y, dlA1.z, dlA1.w};                          \
        float pv[8];                                                                     \
        _Pragma("unroll") for (int q = 0; q < 8; q++) {                                  \
            const float x = srcv + pdst[q];                                              \
            const float l2 = fmaxf(x, 0.01f * x);                                        \
            float e;                                                                     \
            asm("v_exp_f32 %0, %1" : "=v"(e) : "v"(l2 + padj[q]));                       \
            dsum += e;                                                                   \
            pv[q] = e;                                                                   \
        }                                                                                \
        union { unsigned u[4]; short8 s; } pk;                                           \
        asm("v_cvt_pk_bf16_f32 %0, %1, %2" : "=v"(pk.u[0]) : "v"(pv[0]), "v"(pv[1]));    \
        asm("v_cvt_pk_bf16_f32 %0, %1, %2" : "=v"(pk.u[1]) : "v"(pv[2]), "v"(pv[3]));    \
        asm("v_cvt_pk_bf16_f32 %0, %1, %2" : "=v"(pk.u[2]) : "v"(pv[4]), "v"(pv[5]));    \
        asm("v_cvt_pk_bf16_f32 %0, %1, %2" : "=v"(pk.u[3]) : "v"(pv[6]), "v"(pv[7]));    \
        pfrag = pk.s;                                                                    \
    }

#define PV(VBUF, PBUF)                                                                   \
    {                                                                                    \
        const char* vbp = (VBUF);                                                        \
        const char* pbp = (PBUF);                                                        \
        short8 afr[4];                                                                   \
        _Pragma("unroll") for (int t = 0; t < 4; t++) {                                  \
            const int rr = ih * 64 + t * 16 + lr;                                        \
            const int sl = (((rr & 1) << 2) | lc) ^ ((rr >> 1) & 7);                     \
            afr[t] = *(const short8*)(pbp + (rr >> 1) * 128 + (sl << 4));                \
        }                                                                                \
        __builtin_amdgcn_s_setprio(1);                                                   \
        _Pragma("unroll") for (int s = 0; s < 8; s++) {                                  \
            const int d = dq * 128 + s * 16 + lr;                                        \
            const int sl = (((d & 1) << 2) | lc) ^ ((d >> 1) & 7);                       \
            const short8 bfr = *(const short8*)(vbp + (d >> 1) * 128 + (sl << 4));       \
            _Pragma("unroll") for (int t = 0; t < 4; t++)                                \
                acc[t][s] = __builtin_amdgcn_mfma_f32_16x16x32_bf16(afr[t], bfr,         \
                                                                    acc[t][s], 0, 0, 0); \
        }                                                                                \
        __builtin_amdgcn_s_setprio(0);                                                   \
    }

#define WAITBAR(N)                                                                       \
    asm volatile("s_waitcnt vmcnt(" #N ") lgkmcnt(0)" ::: "memory");                     \
    __builtin_amdgcn_sched_barrier(0);                                                   \
    __builtin_amdgcn_s_barrier();                                                        \
    __builtin_amdgcn_sched_barrier(0);

// body(jb): dstL(jb+1) regs (2) + V(jb+1) stage (4) + adj(jb+2) stage (2) = 8 vmem;
// barrier keeps this body's 8 in flight; PV(jb); SCORE(jb+1) from LDS adj; P(jb+1).
#define BODY(JB, VC_, VS_, AR_, AS_, PR_, PW_)                       \
    dlA0 = *(const float4*)(dlp + ((JB) + 1) * 32);                  \
    dlA1 = *(const float4*)(dlp + ((JB) + 1) * 32 + 4);              \
    STAGE(((JB) + 1) * 32, VS_);                                     \
    STAGE_ADJ((JB) >= 254 ? 8160 : ((JB) + 2) * 32, AS_);            \
    WAITBAR(8);                                                      \
    PV(VC_, PR_);                                                    \
    SCORE(AR_, ((JB) + 1) * 32);                                     \
    *(short8*)(PW_ + poff) = pfrag;

    float4 dlA0, dlA1;
    short8 pfrag;
    // ---- prologue: adj(0)->ab0, adj(1)->ab1, V(0)->vb0, dstL(0); score tile 0 ----
    STAGE_ADJ(0, ab0);
    STAGE_ADJ(32, ab1);
    STAGE(0, vb0);
    dlA0 = *(const float4*)(dlp);
    dlA1 = *(const float4*)(dlp + 4);
    WAITBAR(0);
    SCORE(ab0, 0);
    *(short8*)(pb0 + poff) = pfrag;
    // ---- steady state: 255 bodies, 6-unrolled (V/adj mod 3, P mod 2) ----
#pragma unroll 1
    for (int jb = 0; jb < 252; jb += 6) {
        BODY(jb + 0, vb0, vb1, ab1, ab2, pb0, pb1);
        BODY(jb + 1, vb1, vb2, ab2, ab0, pb1, pb0);
        BODY(jb + 2, vb2, vb0, ab0, ab1, pb0, pb1);
        BODY(jb + 3, vb0, vb1, ab1, ab2, pb1, pb0);
        BODY(jb + 4, vb1, vb2, ab2, ab0, pb0, pb1);
        BODY(jb + 5, vb2, vb0, ab0, ab1, pb1, pb0);
    }
    BODY(252, vb0, vb1, ab1, ab2, pb0, pb1);
    BODY(253, vb1, vb2, ab2, ab0, pb1, pb0);
    BODY(254, vb2, vb0, ab0, ab1, pb0, pb1);
    // ---- tail: tile 255 ----
    WAITBAR(0);
    PV(vb0, pb1);

    // --- denominators (denom aliases ab0; all adj reads fenced by tail barrier) ---
    dsum += __shfl_xor(dsum, 16, 64);
    dsum += __shfl_xor(dsum, 32, 64);
    if (lane < 16) denom[w * 16 + lane] = dsum;
    __syncthreads();
    // --- epilogue: out[i][d] += 0.25 * acc / denom ---
#pragma unroll
    for (int t = 0; t < 4; t++) {
        const int rl = ih * 64 + t * 16 + lc * 4;
#pragma unroll
        for (int q = 0; q < 4; q++) {
            const float inv = 0.25f / denom[rl + q];
            float* orow = out + (size_t)(i0 + rl + q) * 512;
#pragma unroll
            for (int s = 0; s < 8; s++) {
                const int d = dq * 128 + s * 16 + lr;
                __hip_atomic_fetch_add(orow + d, acc[t][s][q] * inv,
                                       __ATOMIC_RELAXED, __HIP_MEMORY_SCOPE_AGENT);
            }
        }
    }
}

extern "C" void kernel_launch(void* const* d_in, const int* in_sizes, int n_in,
                              void* d_out, int out_size, void* d_ws, size_t ws_size,
                              hipStream_t stream) {
    const float* h = (const float*)d_in[0];
    const float* adj = (const float*)d_in[1];
    const float* W = (const float*)d_in[2];
    const float* a = (const float*)d_in[3];
    float* out = (float*)d_out;
    char* ws = (char*)d_ws;
    unsigned short* hb = (unsigned short*)ws;                                  // 8 MB
    unsigned short* Wt = (unsigned short*)(ws + 8388608);                      // 2 MB
    unsigned short* vt = (unsigned short*)(ws + 8388608 + 2097152);            // 32 MB
    float* srcL = (float*)(ws + 8388608 + 2097152 + 33554432);                 // 128 KB
    float* dstL = srcL + NH * NN;                                              // 128 KB

    hipMemsetAsync(d_out, 0, (size_t)out_size * sizeof(float), stream);
    hipMemsetAsync(srcL, 0, 2 * NH * NN * sizeof(float), stream);
    k_convert_h<<<2048, 256, 0, stream>>>(h, hb);
    k_transpose_W<<<dim3(64, 16), 256, 0, stream>>>(W, Wt);
    k_gemm<<<dim3(64, 16), 256, 0, stream>>>(Wt, hb, vt, a, srcL, dstL);
    k_flash<<<256, 512, 0, stream>>>(adj, vt, srcL, dstL, out);
}

// Round 8
// 858.130 us; speedup vs baseline: 1.2881x; 1.0053x over previous
//
#include <hip/hip_runtime.h>
#include <stdint.h>

#define NN 8192
#define DH 512
#define NH 4
#define LOG2E 1.4426950408889634f

typedef __attribute__((ext_vector_type(8))) short short8;
typedef __attribute__((ext_vector_type(4))) float f32x4;

__device__ __forceinline__ unsigned short f2bf(float f) {
    unsigned int u = __float_as_uint(f);
    unsigned int r = (u + 0x7fffu + ((u >> 16) & 1u)) >> 16;
    return (unsigned short)r;
}

__device__ __forceinline__ void global_to_lds16(const void* g, void* l) {
    __builtin_amdgcn_global_load_lds(
        (const __attribute__((address_space(1))) unsigned int*)g,
        (__attribute__((address_space(3))) unsigned int*)l, 16, 0, 0);
}

// ---------------- kernel 0a: h fp32 -> bf16 ----------------
__global__ void k_convert_h(const float* __restrict__ hf, unsigned short* __restrict__ hb) {
    const int idx = (blockIdx.x * 256 + threadIdx.x) * 8;
    const float4 f0 = *(const float4*)(hf + idx);
    const float4 f1 = *(const float4*)(hf + idx + 4);
    uint4 o;
    o.x = (unsigned)f2bf(f0.x) | ((unsigned)f2bf(f0.y) << 16);
    o.y = (unsigned)f2bf(f0.z) | ((unsigned)f2bf(f0.w) << 16);
    o.z = (unsigned)f2bf(f1.x) | ((unsigned)f2bf(f1.y) << 16);
    o.w = (unsigned)f2bf(f1.z) | ((unsigned)f2bf(f1.w) << 16);
    *(uint4*)(hb + idx) = o;
}

// ---------------- kernel 0b: W (512x2048) fp32 -> Wt (2048x512) bf16 ----------------
__global__ void k_transpose_W(const float* __restrict__ W, unsigned short* __restrict__ Wt) {
    __shared__ float t[32][33];
    const int tx = threadIdx.x & 31, ty = threadIdx.x >> 5;
    const int p0 = blockIdx.x * 32, k0 = blockIdx.y * 32;
#pragma unroll
    for (int r = 0; r < 4; r++)
        t[ty + r * 8][tx] = W[(k0 + ty + r * 8) * 2048 + p0 + tx];
    __syncthreads();
#pragma unroll
    for (int r = 0; r < 4; r++)
        Wt[(size_t)(p0 + ty + r * 8) * 512 + k0 + tx] = f2bf(t[tx][ty + r * 8]);
}

// ---------------- kernel 1: vt = Wt @ hb^T, fused src/dst projections ----------------
__global__ __launch_bounds__(256, 3) void k_gemm(const unsigned short* __restrict__ Wt,
                                                 const unsigned short* __restrict__ hb,
                                                 unsigned short* __restrict__ vt,
                                                 const float* __restrict__ a,
                                                 float* __restrict__ srcL,
                                                 float* __restrict__ dstL) {
    __shared__ alignas(16) char smem[32768];
    const int tid = threadIdx.x;
    const int w = tid >> 6, lane = tid & 63;
    const int lr = lane & 15, lc = lane >> 4;
    const int pBase = blockIdx.y * 128, nBase = blockIdx.x * 128;
    f32x4 acc[4][4] = {};
    const int wr = (w >> 1) * 64, wc = (w & 1) * 64;
    for (int kb = 0; kb < 8; kb++) {
        const int k0 = kb * 64;
#pragma unroll
        for (int it = 0; it < 4; it++) {
            const int o = it * 4096 + w * 1024 + lane * 16;
            const int row = o >> 7;
            const int koff = (o & 127) >> 1;
            global_to_lds16(Wt + (size_t)(pBase + row) * 512 + k0 + koff,
                            smem + it * 4096 + w * 1024);
            global_to_lds16(hb + (size_t)(nBase + row) * 512 + k0 + koff,
                            smem + 16384 + it * 4096 + w * 1024);
        }
        __syncthreads();
#pragma unroll
        for (int kk = 0; kk < 2; kk++) {
            short8 av[4], bv[4];
#pragma unroll
            for (int m = 0; m < 4; m++)
                av[m] = *(const short8*)(smem + (wr + m * 16 + lr) * 128 + kk * 64 + lc * 16);
#pragma unroll
            for (int n = 0; n < 4; n++)
                bv[n] = *(const short8*)(smem + 16384 + (wc + n * 16 + lr) * 128 + kk * 64 + lc * 16);
#pragma unroll
            for (int m = 0; m < 4; m++)
#pragma unroll
                for (int n = 0; n < 4; n++)
                    acc[m][n] = __builtin_amdgcn_mfma_f32_16x16x32_bf16(av[m], bv[n], acc[m][n], 0, 0, 0);
        }
        __syncthreads();
    }
#pragma unroll
    for (int m = 0; m < 4; m++)
#pragma unroll
        for (int n = 0; n < 4; n++)
#pragma unroll
            for (int q = 0; q < 4; q++) {
                const int p = pBase + wr + m * 16 + lc * 4 + q;
                const int ncol = nBase + wc + n * 16 + lr;
                vt[(size_t)p * NN + ncol] = f2bf(acc[m][n][q]);
            }
    const int hh = pBase >> 9;
    const float* __restrict__ ah = a + hh * 1024;
    float ssum[4] = {0.f, 0.f, 0.f, 0.f}, tsum[4] = {0.f, 0.f, 0.f, 0.f};
#pragma unroll
    for (int m = 0; m < 4; m++) {
        const int dbase = (pBase & 511) + wr + m * 16 + lc * 4;
#pragma unroll
        for (int q = 0; q < 4; q++) {
            const float as = ah[dbase + q];
            const float ad = ah[512 + dbase + q];
#pragma unroll
            for (int n = 0; n < 4; n++) {
                ssum[n] += acc[m][n][q] * as;
                tsum[n] += acc[m][n][q] * ad;
            }
        }
    }
#pragma unroll
    for (int n = 0; n < 4; n++) {
        ssum[n] += __shfl_xor(ssum[n], 16, 64);
        ssum[n] += __shfl_xor(ssum[n], 32, 64);
        tsum[n] += __shfl_xor(tsum[n], 16, 64);
        tsum[n] += __shfl_xor(tsum[n], 32, 64);
    }
    if (lane < 16) {
#pragma unroll
        for (int n = 0; n < 4; n++) {
            const int ncol = nBase + wc + n * 16 + lane;
            __hip_atomic_fetch_add(&srcL[hh * NN + ncol], ssum[n] * LOG2E,
                                   __ATOMIC_RELAXED, __HIP_MEMORY_SCOPE_AGENT);
            __hip_atomic_fetch_add(&dstL[hh * NN + ncol], tsum[n] * LOG2E,
                                   __ATOMIC_RELAXED, __HIP_MEMORY_SCOPE_AGENT);
        }
    }
}

// ---------------- kernel 3: fused masked-softmax attention + PV + mean ----------------
// 256 blocks; h=bid>>6, i0=(bid&63)*128 -> same-i0 head-blocks land on one XCD (adj L2
// dedup). 8 waves. Triple-V depth-1 stage, P double, adj+dstL regs depth-1 (L2-hot),
// counted vmcnt(8), 1 raw barrier/body, SCORE sandwiched between PV halves.
#define NJT (NN / 32)
__global__ __launch_bounds__(512, 2) void k_flash(const float* __restrict__ adj,
                                                  const unsigned short* __restrict__ vt,
                                                  const float* __restrict__ srcL,
                                                  const float* __restrict__ dstL,
                                                  float* __restrict__ out) {
    __shared__ alignas(16) char smem[115200];  // V 3x32K | P 2x8K | denom 512B
    char* const vb0 = smem;
    char* const vb1 = smem + 32768;
    char* const vb2 = smem + 65536;
    char* const pb0 = smem + 98304;
    char* const pb1 = smem + 106496;
    float* denom = (float*)(smem + 114688);

    const int tid = threadIdx.x;
    const int w = tid >> 6, lane = tid & 63;
    const int lr = lane & 15, lc = lane >> 4;
    const int h = (int)(blockIdx.x >> 6);
    const int i0 = (int)(blockIdx.x & 63) * 128;
    const int ih = w >> 2, dq = w & 3;

    const int srow = i0 + w * 16 + lr;
    const float srcv = srcL[h * NN + srow];
    const float* __restrict__ adjp = adj + (size_t)srow * NN + lc * 8;
    const float* __restrict__ dlp = dstL + h * NN + lc * 8;
    const unsigned short* __restrict__ vth = vt + (size_t)(h * 512) * NN;
    float dsum = 0.f;
    f32x4 acc[4][8] = {};

    // V stage source offsets (element units), paired-row XOR layout
    unsigned voff[4];
#pragma unroll
    for (int it = 0; it < 4; it++) {
        const int o = it * 8192 + w * 1024 + lane * 16;
        const int row = o >> 7;
        const int z = ((o >> 4) & 7) ^ (row & 7);
        const int d = (row << 1) | (z >> 2);
        voff[it] = (unsigned)d * NN + ((z & 3) << 3);
    }
    // P write slot (row r = w*16+lr, j-chunk lc), paired-row XOR layout
    const int prow = w * 16 + lr;
    const int psl = (((prow & 1) << 2) | lc) ^ ((prow >> 1) & 7);
    const int poff = (prow >> 1) * 128 + (psl << 4);

#define STAGE(J0, DST)                                                                   \
    {                                                                                    \
        _Pragma("unroll") for (int it = 0; it < 4; it++)                                 \
            global_to_lds16(vth + voff[it] + (J0), (DST) + it * 8192 + w * 1024);        \
    }

#define LOADROW(J0)                                                                      \
    aj0 = *(const float4*)(adjp + (J0));                                                 \
    aj1 = *(const float4*)(adjp + (J0) + 4);                                             \
    dl0 = *(const float4*)(dlp + (J0));                                                  \
    dl1 = *(const float4*)(dlp + (J0) + 4);

#define SCORE()                                                                          \
    {                                                                                    \
        const float padj[8] = {aj0.x, aj0.y, aj0.z, aj0.w, aj1.x, aj1.y, aj1.z, aj1.w};  \
        const float pdst[8] = {dl0.x, dl0.y, dl0.z, dl0.w, dl1.x, dl1.y, dl1.z, dl1.w};  \
        union { unsigned u[4]; short8 s; } pk;                                           \
        _Pragma("unroll") for (int q = 0; q < 4; q++) {                                  \
            const float xa = srcv + pdst[2 * q];                                         \
            const float xb = srcv + pdst[2 * q + 1];                                     \
            const float la = fmaxf(xa, 0.01f * xa) + padj[2 * q];                        \
            const float lb = fmaxf(xb, 0.01f * xb) + padj[2 * q + 1];                    \
            float ea, eb;                                                                \
            asm("v_exp_f32 %0, %1" : "=v"(ea) : "v"(la));                                \
            asm("v_exp_f32 %0, %1" : "=v"(eb) : "v"(lb));                                \
            asm("v_cvt_pk_bf16_f32 %0, %1, %2" : "=v"(pk.u[q]) : "v"(ea), "v"(eb));      \
            dsum += ea + eb;                                                             \
        }                                                                                \
        pfrag = pk.s;                                                                    \
    }

#define AFR(PBUF)                                                                        \
    {                                                                                    \
        _Pragma("unroll") for (int t = 0; t < 4; t++) {                                  \
            const int rr = ih * 64 + t * 16 + lr;                                        \
            const int sl = (((rr & 1) << 2) | lc) ^ ((rr >> 1) & 7);                     \
            afr[t] = *(const short8*)((PBUF) + (rr >> 1) * 128 + (sl << 4));             \
        }                                                                                \
    }

#define PVH(VBUF, HALF)                                                                  \
    {                                                                                    \
        const char* vbp = (VBUF);                                                        \
        __builtin_amdgcn_s_setprio(1);                                                   \
        _Pragma("unroll") for (int s = (HALF) * 4; s < (HALF) * 4 + 4; s++) {            \
            const int d = dq * 128 + s * 16 + lr;                                        \
            const int sl = (((d & 1) << 2) | lc) ^ ((d >> 1) & 7);                       \
            const short8 bfr = *(const short8*)(vbp + (d >> 1) * 128 + (sl << 4));       \
            _Pragma("unroll") for (int t = 0; t < 4; t++)                                \
                acc[t][s] = __builtin_amdgcn_mfma_f32_16x16x32_bf16(afr[t], bfr,         \
                                                                    acc[t][s], 0, 0, 0); \
        }                                                                                \
        __builtin_amdgcn_s_setprio(0);                                                   \
    }

#define WAITBAR(N)                                                                       \
    asm volatile("s_waitcnt vmcnt(" #N ") lgkmcnt(0)" ::: "memory");                     \
    __builtin_amdgcn_sched_barrier(0);                                                   \
    __builtin_amdgcn_s_barrier();                                                        \
    __builtin_amdgcn_sched_barrier(0);

// body(jb): load adj/dstL(jb+1) regs (4 vmem) + stage V(jb+1) (4); barrier with this
// body's 8 in flight; PV-half0(jb); SCORE(jb+1); PV-half1(jb); write P(jb+1).
#define BODY(JB, VC_, VS_, PR_, PW_)   \
    LOADROW(((JB) + 1) * 32);          \
    STAGE(((JB) + 1) * 32, VS_);       \
    WAITBAR(8);                        \
    AFR(PR_);                          \
    PVH(VC_, 0);                       \
    SCORE();                           \
    PVH(VC_, 1);                       \
    *(short8*)(PW_ + poff) = pfrag;

    float4 aj0, aj1, dl0, dl1;
    short8 pfrag;
    short8 afr[4];
    // ---- prologue: adj/dstL(0), V(0)->vb0; score tile 0 -> pb0 ----
    LOADROW(0);
    STAGE(0, vb0);
    WAITBAR(0);
    SCORE();
    *(short8*)(pb0 + poff) = pfrag;
    // ---- steady state: bodies 0..254, 6-unrolled (V mod 3, P mod 2) ----
#pragma unroll 1
    for (int jb = 0; jb < 252; jb += 6) {
        BODY(jb + 0, vb0, vb1, pb0, pb1);
        BODY(jb + 1, vb1, vb2, pb1, pb0);
        BODY(jb + 2, vb2, vb0, pb0, pb1);
        BODY(jb + 3, vb0, vb1, pb1, pb0);
        BODY(jb + 4, vb1, vb2, pb0, pb1);
        BODY(jb + 5, vb2, vb0, pb1, pb0);
    }
    BODY(252, vb0, vb1, pb0, pb1);
    BODY(253, vb1, vb2, pb1, pb0);
    BODY(254, vb2, vb0, pb0, pb1);  // stages V(255)->vb0, scores 255 -> pb1
    // ---- tail: tile 255 ----
    WAITBAR(0);
    AFR(pb1);
    PVH(vb0, 0);
    PVH(vb0, 1);

    // --- denominators: reduce 4 lane-partials per row ---
    dsum += __shfl_xor(dsum, 16, 64);
    dsum += __shfl_xor(dsum, 32, 64);
    if (lane < 16) denom[w * 16 + lane] = dsum;
    __syncthreads();
    // --- epilogue: out[i][d] += 0.25 * acc / denom ---
#pragma unroll
    for (int t = 0; t < 4; t++) {
        const int rl = ih * 64 + t * 16 + lc * 4;
#pragma unroll
        for (int q = 0; q < 4; q++) {
            const float inv = 0.25f / denom[rl + q];
            float* orow = out + (size_t)(i0 + rl + q) * 512;
#pragma unroll
            for (int s = 0; s < 8; s++) {
                const int d = dq * 128 + s * 16 + lr;
                __hip_atomic_fetch_add(orow + d, acc[t][s][q] * inv,
                                       __ATOMIC_RELAXED, __HIP_MEMORY_SCOPE_AGENT);
            }
        }
    }
}

extern "C" void kernel_launch(void* const* d_in, const int* in_sizes, int n_in,
                              void* d_out, int out_size, void* d_ws, size_t ws_size,
                              hipStream_t stream) {
    const float* h = (const float*)d_in[0];
    const float* adj = (const float*)d_in[1];
    const float* W = (const float*)d_in[2];
    const float* a = (const float*)d_in[3];
    float* out = (float*)d_out;
    char* ws = (char*)d_ws;
    unsigned short* hb = (unsigned short*)ws;                                  // 8 MB
    unsigned short* Wt = (unsigned short*)(ws + 8388608);                      // 2 MB
    unsigned short* vt = (unsigned short*)(ws + 8388608 + 2097152);            // 32 MB
    float* srcL = (float*)(ws + 8388608 + 2097152 + 33554432);                 // 128 KB
    float* dstL = srcL + NH * NN;                                              // 128 KB

    hipMemsetAsync(d_out, 0, (size_t)out_size * sizeof(float), stream);
    hipMemsetAsync(srcL, 0, 2 * NH * NN * sizeof(float), stream);
    k_convert_h<<<2048, 256, 0, stream>>>(h, hb);
    k_transpose_W<<<dim3(64, 16), 256, 0, stream>>>(W, Wt);
    k_gemm<<<dim3(64, 16), 256, 0, stream>>>(Wt, hb, vt, a, srcL, dstL);
    k_flash<<<256, 512, 0, stream>>>(adj, vt, srcL, dstL, out);
}